// Round 1
// baseline (170.243 us; speedup 1.0000x reference)
//
#include <hip/hip_runtime.h>
#include <math.h>

#define PP 4096   // P = H*W
#define CC 256    // channels
#define NN 2      // batch

typedef __attribute__((ext_vector_type(8))) short short8;
typedef __attribute__((ext_vector_type(4))) float f32x4;

__device__ __forceinline__ short f2bf(float x) {
    union { float f; unsigned u; } un; un.f = x;
    unsigned r = un.u + 0x7fffu + ((un.u >> 16) & 1u);  // RNE to bf16
    return (short)(r >> 16);
}

// ---- kernel 1: meanT[c] = mean over (n, p) of T ----
__global__ __launch_bounds__(256) void mean_kernel(const float* __restrict__ T,
                                                   float* __restrict__ meanT) {
    int c = blockIdx.x, tid = threadIdx.x;
    float s = 0.f;
    for (int n = 0; n < NN; n++)
        for (int p = tid; p < PP; p += 256)
            s += T[(size_t)(n * CC + c) * PP + p];
    __shared__ float red[256];
    red[tid] = s; __syncthreads();
    for (int st = 128; st > 0; st >>= 1) {
        if (tid < st) red[tid] += red[tid + st];
        __syncthreads();
    }
    if (tid == 0) meanT[c] = red[0] * (1.0f / (NN * PP));
}

// ---- kernel 2: center by meanT, L2-normalize over C, write bf16 transposed [n][p][c] ----
__global__ __launch_bounds__(256) void normalize_kernel(const float* __restrict__ I,
                                                        const float* __restrict__ T,
                                                        const float* __restrict__ meanT,
                                                        short* __restrict__ InT,
                                                        short* __restrict__ TnT) {
    int pc = blockIdx.x * 32;      // 32 positions per block
    int n = blockIdx.y;
    int which = blockIdx.z;        // 0: I -> InT, 1: T -> TnT
    const float* X = which ? T : I;
    short* Y = which ? TnT : InT;

    __shared__ float tile[CC][33];   // [c][p_local], padded
    __shared__ float red[8][32];
    __shared__ float invn[32];

    int tid = threadIdx.x;
    int pl = tid & 31, c0 = tid >> 5;   // 8 c-groups x 32 p
    float sq = 0.f;
    for (int c = c0; c < CC; c += 8) {
        float v = X[(size_t)(n * CC + c) * PP + pc + pl] - meanT[c];
        tile[c][pl] = v;
        sq += v * v;
    }
    red[c0][pl] = sq;
    __syncthreads();
    if (tid < 32) {
        float s = 0.f;
        for (int k = 0; k < 8; k++) s += red[k][tid];
        invn[tid] = 1.0f / sqrtf(s);
    }
    __syncthreads();
    // write transposed: row p = pc + r, contiguous c = tid
    for (int r = 0; r < 32; r++) {
        float v = tile[tid][r] * invn[r];
        Y[(size_t)(n * PP + pc + r) * CC + tid] = f2bf(v);
    }
}

// ---- kernel 3: init stats (ws is poisoned 0xAA each call) ----
__global__ __launch_bounds__(256) void init_stats(unsigned* __restrict__ mn,
                                                  float* __restrict__ S,
                                                  float* __restrict__ diagw) {
    int i = blockIdx.x * 256 + threadIdx.x;
    if (i < NN * PP) {
        mn[i] = 0x7f800000u;  // +inf
        S[i] = 0.f;
        diagw[i] = 0.f;
    }
}

// ---- kernels 4/5: NT-GEMM dot[q,p] = sum_c TnT[q][c] * InT[p][c], fused column stats ----
// MODE 0: column (over q) min of raw=(1-dot)/2 -> atomicMin(mn)
// MODE 1: w = exp((1 - raw/(mn+eps))*10); column sum -> atomicAdd(S); diagonal -> diagw
template <int MODE>
__global__ __launch_bounds__(256) void cx_gemm(const short* __restrict__ TnT,
                                               const short* __restrict__ InT,
                                               unsigned* __restrict__ mn_bits,
                                               float* __restrict__ S,
                                               float* __restrict__ diagw) {
    const int n = blockIdx.z;
    const short* A = TnT + (size_t)n * PP * CC;  // A[q*CC + c]
    const short* B = InT + (size_t)n * PP * CC;  // B[p*CC + c]
    const int q0 = blockIdx.y * 64, p0 = blockIdx.x * 64;

    __shared__ __align__(16) short As[64 * 32];
    __shared__ __align__(16) short Bs[64 * 32];
    __shared__ float red[4][64];

    const int tid = threadIdx.x;
    const int lane = tid & 63, wv = tid >> 6;
    const int lm = lane & 15, quad = lane >> 4;

    f32x4 acc[4] = {};

    const int r = tid >> 2, kq = (tid & 3) * 8;   // staging: 64 rows x 32 k
    for (int k0 = 0; k0 < CC; k0 += 32) {
        short8 av = *(const short8*)&A[(size_t)(q0 + r) * CC + k0 + kq];
        short8 bv = *(const short8*)&B[(size_t)(p0 + r) * CC + k0 + kq];
        __syncthreads();  // previous iter's LDS reads done
        *(short8*)&As[r * 32 + kq] = av;
        *(short8*)&Bs[r * 32 + kq] = bv;
        __syncthreads();
        short8 a = *(const short8*)&As[(wv * 16 + lm) * 32 + quad * 8];
#pragma unroll
        for (int j = 0; j < 4; j++) {
            short8 b = *(const short8*)&Bs[(j * 16 + lm) * 32 + quad * 8];
            acc[j] = __builtin_amdgcn_mfma_f32_16x16x32_bf16(a, b, acc[j], 0, 0, 0);
        }
    }

    if (MODE == 0) {
#pragma unroll
        for (int j = 0; j < 4; j++) {
            float m = 1e30f;
#pragma unroll
            for (int i = 0; i < 4; i++) {
                float raw = (1.0f - acc[j][i]) * 0.5f;
                m = fminf(m, raw);
            }
            m = fminf(m, __shfl_xor(m, 16));
            m = fminf(m, __shfl_xor(m, 32));
            if (quad == 0) red[wv][j * 16 + lm] = m;
        }
        __syncthreads();
        if (tid < 64) {
            float m = fminf(fminf(red[0][tid], red[1][tid]),
                            fminf(red[2][tid], red[3][tid]));
            atomicMin(&mn_bits[n * PP + p0 + tid], __float_as_uint(m));
        }
    } else {
#pragma unroll
        for (int j = 0; j < 4; j++) {
            const int col = p0 + j * 16 + lm;  // global p
            float mnv = __uint_as_float(mn_bits[n * PP + col]);
            float inv_mn = 1.0f / (mnv + 1e-5f);
            float s = 0.f;
#pragma unroll
            for (int i = 0; i < 4; i++) {
                float raw = (1.0f - acc[j][i]) * 0.5f;
                float w = expf((1.0f - raw * inv_mn) * 10.0f);
                s += w;
                int q = q0 + wv * 16 + quad * 4 + i;  // global q
                if (q == col) diagw[n * PP + q] = w;  // unique writer
            }
            s += __shfl_xor(s, 16);
            s += __shfl_xor(s, 32);
            if (quad == 0) red[wv][j * 16 + lm] = s;
        }
        __syncthreads();
        if (tid < 64) {
            float s = red[0][tid] + red[1][tid] + red[2][tid] + red[3][tid];
            atomicAdd(&S[n * PP + p0 + tid], s);
        }
    }
}

// ---- kernel 6: loss = mean_n -log(0.5 + 0.5 * mean_q(diagw/S)) ----
__global__ __launch_bounds__(256) void finalize_kernel(const float* __restrict__ S,
                                                       const float* __restrict__ diagw,
                                                       float* __restrict__ out) {
    __shared__ float red[256];
    __shared__ float loss_s;
    int tid = threadIdx.x;
    if (tid == 0) loss_s = 0.f;
    __syncthreads();
    for (int n = 0; n < NN; n++) {
        float t = 0.f;
        for (int i = tid; i < PP; i += 256)
            t += diagw[n * PP + i] / S[n * PP + i];
        red[tid] = t; __syncthreads();
        for (int st = 128; st > 0; st >>= 1) {
            if (tid < st) red[tid] += red[tid + st];
            __syncthreads();
        }
        if (tid == 0) {
            float m = 0.5f + 0.5f * (red[0] / (float)PP);
            loss_s += -logf(m);
        }
        __syncthreads();
    }
    if (tid == 0) out[0] = loss_s * (1.0f / NN);
}

extern "C" void kernel_launch(void* const* d_in, const int* in_sizes, int n_in,
                              void* d_out, int out_size, void* d_ws, size_t ws_size,
                              hipStream_t stream) {
    const float* I = (const float*)d_in[0];
    const float* T = (const float*)d_in[1];
    float* out = (float*)d_out;

    char* ws = (char*)d_ws;
    const size_t SZ_BF = (size_t)NN * PP * CC * sizeof(short);  // 4 MB each
    short* InT = (short*)ws;
    short* TnT = (short*)(ws + SZ_BF);
    float* meanT = (float*)(ws + 2 * SZ_BF);
    unsigned* mn = (unsigned*)(ws + 2 * SZ_BF + 4096);
    float* S = (float*)(ws + 2 * SZ_BF + 4096 + NN * PP * 4);
    float* diagw = (float*)(ws + 2 * SZ_BF + 4096 + 2 * NN * PP * 4);

    mean_kernel<<<CC, 256, 0, stream>>>(T, meanT);
    normalize_kernel<<<dim3(PP / 32, NN, 2), 256, 0, stream>>>(I, T, meanT, InT, TnT);
    init_stats<<<(NN * PP + 255) / 256, 256, 0, stream>>>(mn, S, diagw);
    cx_gemm<0><<<dim3(PP / 64, PP / 64, NN), 256, 0, stream>>>(TnT, InT, mn, S, diagw);
    cx_gemm<1><<<dim3(PP / 64, PP / 64, NN), 256, 0, stream>>>(TnT, InT, mn, S, diagw);
    finalize_kernel<<<1, 256, 0, stream>>>(S, diagw, out);
}

// Round 2
// 140.360 us; speedup vs baseline: 1.2129x; 1.2129x over previous
//
#include <hip/hip_runtime.h>
#include <math.h>

#define PP 4096   // P = H*W
#define CC 256    // channels
#define NN 2      // batch

typedef __attribute__((ext_vector_type(8))) short short8;
typedef __attribute__((ext_vector_type(4))) float f32x4;

__device__ __forceinline__ short f2bf(float x) {
    union { float f; unsigned u; } un; un.f = x;
    unsigned r = un.u + 0x7fffu + ((un.u >> 16) & 1u);  // RNE to bf16
    return (short)(r >> 16);
}

__device__ __forceinline__ void gld_lds16(const short* g, short* l) {
    __builtin_amdgcn_global_load_lds(
        (const __attribute__((address_space(1))) unsigned int*)g,
        (__attribute__((address_space(3))) unsigned int*)l, 16, 0, 0);
}

// ---- kernel 1: meanT[c] = mean over (n,p) of T; also init stats arrays ----
__global__ __launch_bounds__(256) void mean_kernel(const float* __restrict__ T,
                                                   float* __restrict__ meanT,
                                                   unsigned* __restrict__ mn_enc,
                                                   float* __restrict__ S,
                                                   float* __restrict__ diagw) {
    int c = blockIdx.x, tid = threadIdx.x;
    float s = 0.f;
    for (int n = 0; n < NN; n++)
        for (int p = tid; p < PP; p += 256)
            s += T[(size_t)(n * CC + c) * PP + p];
    __shared__ float red[256];
    red[tid] = s; __syncthreads();
    for (int st = 128; st > 0; st >>= 1) {
        if (tid < st) red[tid] += red[tid + st];
        __syncthreads();
    }
    if (tid == 0) meanT[c] = red[0] * (1.0f / (NN * PP));
    // init stats: 256 blocks x 32 entries = NN*PP = 8192
    int base = blockIdx.x * 32;
    if (tid < 32) {
        mn_enc[base + tid] = 0xFFFFFFFFu;  // +inf in monotone-uint encoding
        S[base + tid] = 0.f;
        diagw[base + tid] = 0.f;
    }
}

// ---- kernel 2: center by meanT, L2-normalize over C, write bf16 transposed [n][p][c] ----
__global__ __launch_bounds__(256) void normalize_kernel(const float* __restrict__ I,
                                                        const float* __restrict__ T,
                                                        const float* __restrict__ meanT,
                                                        short* __restrict__ InT,
                                                        short* __restrict__ TnT) {
    int pc = blockIdx.x * 32;      // 32 positions per block
    int n = blockIdx.y;
    int which = blockIdx.z;        // 0: I -> InT, 1: T -> TnT
    const float* X = which ? T : I;
    short* Y = which ? TnT : InT;

    __shared__ float tile[CC][33];   // [c][p_local], padded
    __shared__ float red[8][32];
    __shared__ float invn[32];

    int tid = threadIdx.x;
    int pl = tid & 31, c0 = tid >> 5;   // 8 c-groups x 32 p
    float sq = 0.f;
    for (int c = c0; c < CC; c += 8) {
        float v = X[(size_t)(n * CC + c) * PP + pc + pl] - meanT[c];
        tile[c][pl] = v;
        sq += v * v;
    }
    red[c0][pl] = sq;
    __syncthreads();
    if (tid < 32) {
        float s = 0.f;
        for (int k = 0; k < 8; k++) s += red[k][tid];
        invn[tid] = 1.0f / sqrtf(s);
    }
    __syncthreads();
    // vectorized write: 2 channels per thread, 2 rows per iteration (4B stores)
    for (int rr = 0; rr < 32; rr += 2) {
        int r = rr + (tid >> 7);
        int c2 = (tid & 127) * 2;
        float v0 = tile[c2][r] * invn[r];
        float v1 = tile[c2 + 1][r] * invn[r];
        unsigned pack = ((unsigned)(unsigned short)f2bf(v1) << 16) |
                        (unsigned)(unsigned short)f2bf(v0);
        *(unsigned*)&Y[(size_t)(n * PP + pc + r) * CC + c2] = pack;
    }
}

// ---- kernels 3/4: NT-GEMM dot[q,p] = sum_c TnT[q][c] * InT[p][c], fused column stats ----
// 128x128 tile, 4 waves (each 64x64 via 4x4 16x16x32 MFMA), global_load_lds staging,
// XOR-swizzled k-chunks (chunk ^ ((row>>1)&3)) to break ds_read_b128 bank conflicts.
// MODE 0: column (over q) min of raw=(1-dot)/2 -> atomicMin(mn_enc) [monotone uint]
// MODE 1: w = exp(10 - raw*10/(mn+eps)); column sum -> atomicAdd(S); diagonal -> diagw
template <int MODE>
__global__ __launch_bounds__(256) void cx_gemm(const short* __restrict__ TnT,
                                               const short* __restrict__ InT,
                                               unsigned* __restrict__ mn_enc,
                                               float* __restrict__ S,
                                               float* __restrict__ diagw) {
    const int n = blockIdx.z;
    const short* __restrict__ A = TnT + (size_t)n * PP * CC;  // A[q*CC + c]
    const short* __restrict__ B = InT + (size_t)n * PP * CC;  // B[p*CC + c]
    const int q0 = blockIdx.y * 128, p0 = blockIdx.x * 128;

    __shared__ __align__(16) short As[128 * 32];  // 8 KB
    __shared__ __align__(16) short Bs[128 * 32];  // 8 KB
    __shared__ float red[4][64];

    const int tid = threadIdx.x;
    const int l = tid & 63, wv = tid >> 6;
    const int lm = l & 15, quad = l >> 4;
    const int wr = (wv >> 1) * 64, wc = (wv & 1) * 64;  // wave tile origin
    const int swz = (lm >> 1) & 3;

    // staging: lane l of wave wv covers LDS row wv*16 + (l>>2) (+64 for 2nd issue),
    // global k-chunk = (l&3) ^ ((l>>3)&3); LDS dest = lane-order contiguous (DMA rule)
    const int srow = wv * 16 + (l >> 2);
    const int gk = ((l & 3) ^ ((l >> 3) & 3)) * 8;
    const short* Ag = A + (size_t)(q0 + srow) * CC + gk;
    const short* Bg = B + (size_t)(p0 + srow) * CC + gk;
    short* Al = As + tid * 8;
    short* Bl = Bs + tid * 8;

    f32x4 acc[4][4] = {};

    for (int k0 = 0; k0 < CC; k0 += 32) {
        __syncthreads();  // previous iter's LDS reads done
        gld_lds16(Ag + k0, Al);
        gld_lds16(Ag + 64 * CC + k0, Al + 2048);
        gld_lds16(Bg + k0, Bl);
        gld_lds16(Bg + 64 * CC + k0, Bl + 2048);
        __syncthreads();  // drains vmcnt(0): staged data visible

        short8 a[4], b[4];
#pragma unroll
        for (int i = 0; i < 4; i++)
            a[i] = *(const short8*)&As[(wr + i * 16 + lm) * 32 + (quad ^ swz) * 8];
#pragma unroll
        for (int j = 0; j < 4; j++)
            b[j] = *(const short8*)&Bs[(wc + j * 16 + lm) * 32 + (quad ^ swz) * 8];
#pragma unroll
        for (int i = 0; i < 4; i++)
#pragma unroll
            for (int j = 0; j < 4; j++)
                acc[i][j] = __builtin_amdgcn_mfma_f32_16x16x32_bf16(a[i], b[j], acc[i][j], 0, 0, 0);
    }

    // C/D layout: col = lm, row = quad*4 + reg (within each 16x16 tile)
    if (MODE == 0) {
#pragma unroll
        for (int j = 0; j < 4; j++) {
            float m = 3.4e38f;
#pragma unroll
            for (int i = 0; i < 4; i++)
#pragma unroll
                for (int e = 0; e < 4; e++)
                    m = fminf(m, (1.0f - acc[i][j][e]) * 0.5f);
            m = fminf(m, __shfl_xor(m, 16));
            m = fminf(m, __shfl_xor(m, 32));
            if (quad == 0) red[wv][j * 16 + lm] = m;  // column (wv&1)*64 + j*16 + lm
        }
        __syncthreads();
        if (tid < 128) {
            int half = tid >> 6, idx = tid & 63;
            float m = fminf(red[half][idx], red[2 + half][idx]);
            unsigned u = __float_as_uint(m);
            u = (u & 0x80000000u) ? ~u : (u | 0x80000000u);  // monotone encoding
            atomicMin(&mn_enc[n * PP + p0 + tid], u);
        }
    } else {
#pragma unroll
        for (int j = 0; j < 4; j++) {
            const int c = p0 + wc + j * 16 + lm;  // global p
            unsigned e = mn_enc[n * PP + c];
            unsigned u = (e & 0x80000000u) ? (e & 0x7fffffffu) : ~e;  // decode
            float mnv = __uint_as_float(u);
            float inv = 10.0f / (mnv + 1e-5f);
            float s = 0.f;
#pragma unroll
            for (int i = 0; i < 4; i++)
#pragma unroll
                for (int e2 = 0; e2 < 4; e2++) {
                    float raw = (1.0f - acc[i][j][e2]) * 0.5f;
                    float w = expf(10.0f - raw * inv);
                    s += w;
                    int q = q0 + wr + i * 16 + quad * 4 + e2;  // global q
                    if (q == c) diagw[n * PP + q] = w;         // unique writer
                }
            s += __shfl_xor(s, 16);
            s += __shfl_xor(s, 32);
            if (quad == 0) red[wv][j * 16 + lm] = s;
        }
        __syncthreads();
        if (tid < 128) {
            int half = tid >> 6, idx = tid & 63;
            float s = red[half][idx] + red[2 + half][idx];
            atomicAdd(&S[n * PP + p0 + tid], s);
        }
    }
}

// ---- kernel 5: loss = mean_n -log(0.5 + 0.5 * mean_q(diagw/S)) ----
__global__ __launch_bounds__(1024) void finalize_kernel(const float* __restrict__ S,
                                                        const float* __restrict__ diagw,
                                                        float* __restrict__ out) {
    __shared__ float red[1024];
    __shared__ float loss_s;
    int tid = threadIdx.x;
    if (tid == 0) loss_s = 0.f;
    __syncthreads();
    for (int n = 0; n < NN; n++) {
        float t = 0.f;
        for (int i = tid; i < PP; i += 1024)
            t += diagw[n * PP + i] / S[n * PP + i];
        red[tid] = t; __syncthreads();
        for (int st = 512; st > 0; st >>= 1) {
            if (tid < st) red[tid] += red[tid + st];
            __syncthreads();
        }
        if (tid == 0) {
            float m = 0.5f + 0.5f * (red[0] / (float)PP);
            loss_s += -logf(m);
        }
        __syncthreads();
    }
    if (tid == 0) out[0] = loss_s * (1.0f / NN);
}

extern "C" void kernel_launch(void* const* d_in, const int* in_sizes, int n_in,
                              void* d_out, int out_size, void* d_ws, size_t ws_size,
                              hipStream_t stream) {
    const float* I = (const float*)d_in[0];
    const float* T = (const float*)d_in[1];
    float* out = (float*)d_out;

    char* ws = (char*)d_ws;
    const size_t SZ_BF = (size_t)NN * PP * CC * sizeof(short);  // 4 MB each
    short* InT = (short*)ws;
    short* TnT = (short*)(ws + SZ_BF);
    float* meanT = (float*)(ws + 2 * SZ_BF);
    unsigned* mn = (unsigned*)(ws + 2 * SZ_BF + 4096);
    float* S = (float*)(ws + 2 * SZ_BF + 4096 + NN * PP * 4);
    float* diagw = (float*)(ws + 2 * SZ_BF + 4096 + 2 * NN * PP * 4);

    mean_kernel<<<CC, 256, 0, stream>>>(T, meanT, mn, S, diagw);
    normalize_kernel<<<dim3(PP / 32, NN, 2), 256, 0, stream>>>(I, T, meanT, InT, TnT);
    cx_gemm<0><<<dim3(PP / 128, PP / 128, NN), 256, 0, stream>>>(TnT, InT, mn, S, diagw);
    cx_gemm<1><<<dim3(PP / 128, PP / 128, NN), 256, 0, stream>>>(TnT, InT, mn, S, diagw);
    finalize_kernel<<<1, 1024, 0, stream>>>(S, diagw, out);
}

// Round 3
// 139.405 us; speedup vs baseline: 1.2212x; 1.0069x over previous
//
#include <hip/hip_runtime.h>
#include <math.h>

#define PP 4096   // P = H*W
#define CC 256    // channels
#define NN 2      // batch

typedef __attribute__((ext_vector_type(8))) short short8;
typedef __attribute__((ext_vector_type(4))) float f32x4;

__device__ __forceinline__ short f2bf(float x) {
    union { float f; unsigned u; } un; un.f = x;
    unsigned r = un.u + 0x7fffu + ((un.u >> 16) & 1u);  // RNE to bf16
    return (short)(r >> 16);
}

__device__ __forceinline__ void gld_lds16(const short* g, short* l) {
    __builtin_amdgcn_global_load_lds(
        (const __attribute__((address_space(1))) unsigned int*)g,
        (__attribute__((address_space(3))) unsigned int*)l, 16, 0, 0);
}

// ---- kernel 1: meanT[c] = mean over (n,p) of T; also init stats arrays ----
__global__ __launch_bounds__(256) void mean_kernel(const float* __restrict__ T,
                                                   float* __restrict__ meanT,
                                                   unsigned* __restrict__ mn_enc,
                                                   float* __restrict__ S,
                                                   float* __restrict__ diagw) {
    int c = blockIdx.x, tid = threadIdx.x;
    float s = 0.f;
    for (int n = 0; n < NN; n++)
        for (int p = tid; p < PP; p += 256)
            s += T[(size_t)(n * CC + c) * PP + p];
    __shared__ float red[256];
    red[tid] = s; __syncthreads();
    for (int st = 128; st > 0; st >>= 1) {
        if (tid < st) red[tid] += red[tid + st];
        __syncthreads();
    }
    if (tid == 0) meanT[c] = red[0] * (1.0f / (NN * PP));
    // init stats: 256 blocks x 32 entries = NN*PP = 8192
    int base = blockIdx.x * 32;
    if (tid < 32) {
        mn_enc[base + tid] = 0xFFFFFFFFu;  // +inf in monotone-uint encoding
        S[base + tid] = 0.f;
        diagw[base + tid] = 0.f;
    }
}

// ---- kernel 2: center by meanT, L2-normalize over C, write bf16 transposed [n][p][c] ----
__global__ __launch_bounds__(256) void normalize_kernel(const float* __restrict__ I,
                                                        const float* __restrict__ T,
                                                        const float* __restrict__ meanT,
                                                        short* __restrict__ InT,
                                                        short* __restrict__ TnT) {
    int pc = blockIdx.x * 32;      // 32 positions per block
    int n = blockIdx.y;
    int which = blockIdx.z;        // 0: I -> InT, 1: T -> TnT
    const float* X = which ? T : I;
    short* Y = which ? TnT : InT;

    __shared__ float tile[CC][33];   // [c][p_local], padded
    __shared__ float red[8][32];
    __shared__ float invn[32];

    int tid = threadIdx.x;
    int pl = tid & 31, c0 = tid >> 5;   // 8 c-groups x 32 p
    float sq = 0.f;
    for (int c = c0; c < CC; c += 8) {
        float v = X[(size_t)(n * CC + c) * PP + pc + pl] - meanT[c];
        tile[c][pl] = v;
        sq += v * v;
    }
    red[c0][pl] = sq;
    __syncthreads();
    if (tid < 32) {
        float s = 0.f;
        for (int k = 0; k < 8; k++) s += red[k][tid];
        invn[tid] = 1.0f / sqrtf(s);
    }
    __syncthreads();
    // vectorized write: 2 channels per thread, 2 rows per iteration (4B stores)
    for (int rr = 0; rr < 32; rr += 2) {
        int r = rr + (tid >> 7);
        int c2 = (tid & 127) * 2;
        float v0 = tile[c2][r] * invn[r];
        float v1 = tile[c2 + 1][r] * invn[r];
        unsigned pack = ((unsigned)(unsigned short)f2bf(v1) << 16) |
                        (unsigned)(unsigned short)f2bf(v0);
        *(unsigned*)&Y[(size_t)(n * PP + pc + r) * CC + c2] = pack;
    }
}

// ---- kernels 3/4: NT-GEMM dot[q,p] = sum_c TnT[q][c] * InT[p][c], fused column stats ----
// 128x128 tile, BK=64, 4 waves (each 64x64 via 4x4 16x16x32 MFMA), global_load_lds
// staging, XOR-swizzle: stored slot s of row r holds global 16B-chunk s^(r&7)
// -> coalesced 128B global segments per 8 lanes AND 2-way-max LDS read aliasing.
// __launch_bounds__(256,4): cap regs at 128/wave (64 AGPR acc + ~55 VGPR) -> 4 blk/CU.
// MODE 0: column (over q) min of raw=(1-dot)/2 -> atomicMin(mn_enc) [monotone uint]
// MODE 1: w = exp(10 - raw*10/(mn+eps)); column sum -> atomicAdd(S); diagonal -> diagw
template <int MODE>
__global__ __launch_bounds__(256, 4) void cx_gemm(const short* __restrict__ TnT,
                                                  const short* __restrict__ InT,
                                                  unsigned* __restrict__ mn_enc,
                                                  float* __restrict__ S,
                                                  float* __restrict__ diagw) {
    const int n = blockIdx.z;
    const short* __restrict__ A = TnT + (size_t)n * PP * CC;  // A[q*CC + c]
    const short* __restrict__ B = InT + (size_t)n * PP * CC;  // B[p*CC + c]
    const int q0 = blockIdx.y * 128, p0 = blockIdx.x * 128;

    __shared__ __align__(16) short As[128 * 64];  // 16 KB
    __shared__ __align__(16) short Bs[128 * 64];  // 16 KB
    __shared__ float red[4][64];

    const int tid = threadIdx.x;
    const int l = tid & 63, wv = tid >> 6;
    const int lm = l & 15, quad = l >> 4;
    const int wr = (wv >> 1) * 64, wc = (wv & 1) * 64;  // wave tile origin

    // staging geometry: round t covers rows t*32 + (tid>>3), slot tid&7;
    // global chunk = slot ^ (row&7)  (row&7 == (tid>>3)&7)
    const int srow = tid >> 3;
    const int gk = ((tid & 7) ^ (srow & 7)) * 8;
    const short* Ag = A + (size_t)(q0 + srow) * CC + gk;
    const short* Bg = B + (size_t)(p0 + srow) * CC + gk;
    short* Al = As + tid * 8;
    short* Bl = Bs + tid * 8;

    f32x4 acc[4][4] = {};

    for (int k0 = 0; k0 < CC; k0 += 64) {
        __syncthreads();  // previous iter's LDS reads done
#pragma unroll
        for (int t = 0; t < 4; t++) {
            gld_lds16(Ag + t * 32 * CC + k0, Al + t * 2048);
            gld_lds16(Bg + t * 32 * CC + k0, Bl + t * 2048);
        }
        __syncthreads();  // drains vmcnt(0): staged data visible

#pragma unroll
        for (int ksub = 0; ksub < 2; ksub++) {
            short8 a[4], b[4];
            const int c = ksub * 4 + quad;  // logical 8-elem chunk
#pragma unroll
            for (int i = 0; i < 4; i++) {
                int row = wr + i * 16 + lm;
                a[i] = *(const short8*)&As[row * 64 + (c ^ (lm & 7)) * 8];
            }
#pragma unroll
            for (int j = 0; j < 4; j++) {
                int row = wc + j * 16 + lm;
                b[j] = *(const short8*)&Bs[row * 64 + (c ^ (lm & 7)) * 8];
            }
#pragma unroll
            for (int i = 0; i < 4; i++)
#pragma unroll
                for (int j = 0; j < 4; j++)
                    acc[i][j] = __builtin_amdgcn_mfma_f32_16x16x32_bf16(a[i], b[j], acc[i][j], 0, 0, 0);
        }
    }

    // C/D layout: col = lm, row = quad*4 + reg (within each 16x16 tile)
    if (MODE == 0) {
#pragma unroll
        for (int j = 0; j < 4; j++) {
            float m = 3.4e38f;
#pragma unroll
            for (int i = 0; i < 4; i++)
#pragma unroll
                for (int e = 0; e < 4; e++)
                    m = fminf(m, (1.0f - acc[i][j][e]) * 0.5f);
            m = fminf(m, __shfl_xor(m, 16));
            m = fminf(m, __shfl_xor(m, 32));
            if (quad == 0) red[wv][j * 16 + lm] = m;  // column (wv&1)*64 + j*16 + lm
        }
        __syncthreads();
        if (tid < 128) {
            int half = tid >> 6, idx = tid & 63;
            float m = fminf(red[half][idx], red[2 + half][idx]);
            unsigned u = __float_as_uint(m);
            u = (u & 0x80000000u) ? ~u : (u | 0x80000000u);  // monotone encoding
            atomicMin(&mn_enc[n * PP + p0 + tid], u);
        }
    } else {
#pragma unroll
        for (int j = 0; j < 4; j++) {
            const int c = p0 + wc + j * 16 + lm;  // global p
            unsigned e = mn_enc[n * PP + c];
            unsigned u = (e & 0x80000000u) ? (e & 0x7fffffffu) : ~e;  // decode
            float mnv = __uint_as_float(u);
            float inv = 10.0f / (mnv + 1e-5f);
            float s = 0.f;
#pragma unroll
            for (int i = 0; i < 4; i++)
#pragma unroll
                for (int e2 = 0; e2 < 4; e2++) {
                    float raw = (1.0f - acc[i][j][e2]) * 0.5f;
                    float w = expf(10.0f - raw * inv);
                    s += w;
                    int q = q0 + wr + i * 16 + quad * 4 + e2;  // global q
                    if (q == c) diagw[n * PP + q] = w;         // unique writer
                }
            s += __shfl_xor(s, 16);
            s += __shfl_xor(s, 32);
            if (quad == 0) red[wv][j * 16 + lm] = s;
        }
        __syncthreads();
        if (tid < 128) {
            int half = tid >> 6, idx = tid & 63;
            float s = red[half][idx] + red[2 + half][idx];
            atomicAdd(&S[n * PP + p0 + tid], s);
        }
    }
}

// ---- kernel 5: loss = mean_n -log(0.5 + 0.5 * mean_q(diagw/S)) ----
__global__ __launch_bounds__(1024) void finalize_kernel(const float* __restrict__ S,
                                                        const float* __restrict__ diagw,
                                                        float* __restrict__ out) {
    __shared__ float red[1024];
    __shared__ float loss_s;
    int tid = threadIdx.x;
    if (tid == 0) loss_s = 0.f;
    __syncthreads();
    for (int n = 0; n < NN; n++) {
        float t = 0.f;
        for (int i = tid; i < PP; i += 1024)
            t += diagw[n * PP + i] / S[n * PP + i];
        red[tid] = t; __syncthreads();
        for (int st = 512; st > 0; st >>= 1) {
            if (tid < st) red[tid] += red[tid + st];
            __syncthreads();
        }
        if (tid == 0) {
            float m = 0.5f + 0.5f * (red[0] / (float)PP);
            loss_s += -logf(m);
        }
        __syncthreads();
    }
    if (tid == 0) out[0] = loss_s * (1.0f / NN);
}

extern "C" void kernel_launch(void* const* d_in, const int* in_sizes, int n_in,
                              void* d_out, int out_size, void* d_ws, size_t ws_size,
                              hipStream_t stream) {
    const float* I = (const float*)d_in[0];
    const float* T = (const float*)d_in[1];
    float* out = (float*)d_out;

    char* ws = (char*)d_ws;
    const size_t SZ_BF = (size_t)NN * PP * CC * sizeof(short);  // 4 MB each
    short* InT = (short*)ws;
    short* TnT = (short*)(ws + SZ_BF);
    float* meanT = (float*)(ws + 2 * SZ_BF);
    unsigned* mn = (unsigned*)(ws + 2 * SZ_BF + 4096);
    float* S = (float*)(ws + 2 * SZ_BF + 4096 + NN * PP * 4);
    float* diagw = (float*)(ws + 2 * SZ_BF + 4096 + 2 * NN * PP * 4);

    mean_kernel<<<CC, 256, 0, stream>>>(T, meanT, mn, S, diagw);
    normalize_kernel<<<dim3(PP / 32, NN, 2), 256, 0, stream>>>(I, T, meanT, InT, TnT);
    cx_gemm<0><<<dim3(PP / 128, PP / 128, NN), 256, 0, stream>>>(TnT, InT, mn, S, diagw);
    cx_gemm<1><<<dim3(PP / 128, PP / 128, NN), 256, 0, stream>>>(TnT, InT, mn, S, diagw);
    finalize_kernel<<<1, 1024, 0, stream>>>(S, diagw, out);
}